// Round 18
// baseline (1824.467 us; speedup 1.0000x reference)
//
#include <hip/hip_runtime.h>
#include <hip/hip_bf16.h>
#include <math.h>

// PointNet++ SAModule: FPS -> ball query -> PointNetConv(MLP, max-agg)
// B=16, N=4096, S=1024, K=64, r=0.1, MLP 67->64->64->128.
// R18: producer rebuilt as a SINGLE-WAVE chain (64 pts/lane in VGPRs): no
// barrier, no cross-wave select. Wave0 = chain (packed update, 4-chain argmax
// scan, all-lanes butterfly reduce, broadcast LDS read of winner xyz); wave1 =
// publisher (polls LDS cnt, copies hist->histg/out_pos/out_batch, releases
// progress) -- publishing fully off the critical path. Waves 2-3 exit.
// Selection bit-exact vs numpy (R17-proven packed RN math; ascending-index
// first-occurrence preserved per chain + (val,~idx) key merge).
// Consumers (ball + MFMA conv) byte-identical to R12/R17.

#define NB 16
#define NP 4096
#define FIN 64
#define NS 1024
#define KN 64
#define CAP 128
#define NCONS 240
#define NCHUNK 4096

typedef __attribute__((ext_vector_type(8))) short bf16x8;
typedef __attribute__((ext_vector_type(4))) float f32x4;
typedef __attribute__((ext_vector_type(2))) float f32x2;

__device__ __forceinline__ float dist2e(float ax, float ay, float az,
                                        float bx, float by, float bz) {
    float dx = __fsub_rn(ax, bx);
    float dy = __fsub_rn(ay, by);
    float dz = __fsub_rn(az, bz);
    return __fadd_rn(__fadd_rn(__fmul_rn(dx, dx), __fmul_rn(dy, dy)),
                     __fmul_rn(dz, dz));
}

__device__ __forceinline__ short f2bf(float f) {  // RNE fp32 -> bf16 bits
    unsigned u = __float_as_uint(f);
    unsigned r = (u + 0x7FFFu + ((u >> 16) & 1u)) >> 16;
    return (short)r;
}

// DPP row-rotate reduce level on packed u64 key (max). 0x121..0x128 = ror1..8.
#define DPP_KEY_MAX(k, CTRL)                                                   \
    do {                                                                       \
        int _lo = (int)(unsigned)((k) & 0xFFFFFFFFull);                        \
        int _hi = (int)(unsigned)((k) >> 32);                                  \
        int _plo = __builtin_amdgcn_update_dpp(_lo, _lo, CTRL, 0xF, 0xF, false);\
        int _phi = __builtin_amdgcn_update_dpp(_hi, _hi, CTRL, 0xF, 0xF, false);\
        unsigned long long _nk =                                               \
            ((unsigned long long)(unsigned)_phi << 32) | (unsigned)_plo;       \
        if (_nk > (k)) (k) = _nk;                                              \
    } while (0)

// Full all-lanes wave max (R5-proven): 4 DPP rows + ds_swizzle xor16 + shfl32.
#define WAVE_KEY_MAX(k)                                                        \
    do {                                                                       \
        DPP_KEY_MAX(k, 0x121);                                                 \
        DPP_KEY_MAX(k, 0x122);                                                 \
        DPP_KEY_MAX(k, 0x124);                                                 \
        DPP_KEY_MAX(k, 0x128);                                                 \
        {                                                                      \
            int _lo = (int)(unsigned)((k) & 0xFFFFFFFFull);                    \
            int _hi = (int)(unsigned)((k) >> 32);                              \
            int _plo = __builtin_amdgcn_ds_swizzle(_lo, 0x401F);               \
            int _phi = __builtin_amdgcn_ds_swizzle(_hi, 0x401F);               \
            unsigned long long _nk =                                           \
                ((unsigned long long)(unsigned)_phi << 32) | (unsigned)_plo;   \
            if (_nk > (k)) (k) = _nk;                                          \
        }                                                                      \
        {                                                                      \
            unsigned long long _nk = __shfl_xor((k), 32, 64);                  \
            if (_nk > (k)) (k) = _nk;                                          \
        }                                                                      \
    } while (0)

#define SMEM_BYTES 65600

__global__ __launch_bounds__(256, 1) void fused_kernel(
        const float* __restrict__ pos, const float* __restrict__ x,
        const float* __restrict__ W1, const float* __restrict__ b1,
        const float* __restrict__ W2, const float* __restrict__ b2,
        const float* __restrict__ W3, const float* __restrict__ b3,
        float* __restrict__ out_feat, float* __restrict__ out_pos,
        float* __restrict__ out_batch, float* __restrict__ histg,
        int* __restrict__ progress) {
    __shared__ __align__(16) char smem[SMEM_BYTES];
    const int tid = threadIdx.x;
    const int lane = tid & 63;
    const int wv = tid >> 6;

    if (blockIdx.x < NB) {
        // ================== FPS producer: 1-wave chain + publisher ==========
        const int b = blockIdx.x;
        float* px = (float*)smem;                        // [4096] 16KB
        float* py = px + NP;
        float* pz = py + NP;
        float4* hist = (float4*)(smem + 49152);          // [1024] 16KB
        int* cnt = (int*)(smem + 65536);
        const float* p = pos + (size_t)b * NP * 3;
        for (int i = 0; i < 16; ++i) {
            int j = tid + (i << 8);
            px[j] = p[j * 3 + 0];
            py[j] = p[j * 3 + 1];
            pz[j] = p[j * 3 + 2];
        }
        if (tid == 0) {
            *cnt = 0;
            hist[0] = make_float4(0.f, p[0], p[1], p[2]);
        }
        __syncthreads();   // the ONLY producer barrier (before divergence)

        if (wv == 0) {
            // ---------------- chain wave: 64 pts/lane in VGPRs --------------
            f32x2 lx2[32], ly2[32], lz2[32], md2[32];
#pragma unroll
            for (int k = 0; k < 32; ++k) {
#pragma unroll
                for (int e = 0; e < 2; ++e) {
                    int j = ((2 * k + e) << 6) | lane;
                    lx2[k][e] = px[j];
                    ly2[k][e] = py[j];
                    lz2[k][e] = pz[j];
                }
                md2[k] = (f32x2){INFINITY, INFINITY};
            }
            float cx = px[0], cy = py[0], cz = pz[0];
            for (int s = 1; s < NS; ++s) {
                // packed md update (RN per element, no contraction -> exact)
                {
#pragma clang fp contract(off)
                    const f32x2 cx2 = (f32x2){cx, cx};
                    const f32x2 cy2 = (f32x2){cy, cy};
                    const f32x2 cz2 = (f32x2){cz, cz};
#pragma unroll
                    for (int k = 0; k < 32; ++k) {
                        f32x2 dx = lx2[k] - cx2;
                        f32x2 dy = ly2[k] - cy2;
                        f32x2 dz = lz2[k] - cz2;
                        f32x2 d = (dx * dx + dy * dy) + dz * dz;
                        f32x2 m = md2[k];
                        m[0] = d[0] < m[0] ? d[0] : m[0];  // jnp.minimum
                        m[1] = d[1] < m[1] ? d[1] : m[1];
                        md2[k] = m;
                    }
                }
                // 4-chain argmax scan (each chain ascending element index,
                // strict > => first occurrence; merge ties -> lower index)
                float v0 = -1.f, v1 = -1.f, v2 = -1.f, v3 = -1.f;
                int e0 = 0, e1 = 0, e2 = 0, e3 = 0;
#pragma unroll
                for (int m4 = 0; m4 < 16; ++m4) {
                    float a0 = md2[2 * m4][0];
                    float a1 = md2[2 * m4][1];
                    float a2 = md2[2 * m4 + 1][0];
                    float a3 = md2[2 * m4 + 1][1];
                    bool t;
                    t = a0 > v0; v0 = t ? a0 : v0; e0 = t ? (4 * m4 + 0) : e0;
                    t = a1 > v1; v1 = t ? a1 : v1; e1 = t ? (4 * m4 + 1) : e1;
                    t = a2 > v2; v2 = t ? a2 : v2; e2 = t ? (4 * m4 + 2) : e2;
                    t = a3 > v3; v3 = t ? a3 : v3; e3 = t ? (4 * m4 + 3) : e3;
                }
                bool t01 = (v1 > v0) || (v1 == v0 && e1 < e0);
                float va = t01 ? v1 : v0;
                int ea = t01 ? e1 : e0;
                bool t23 = (v3 > v2) || (v3 == v2 && e3 < e2);
                float vb = t23 ? v3 : v2;
                int eb = t23 ? e3 : e2;
                bool tab = (vb > va) || (vb == va && eb < ea);
                float bv = tab ? vb : va;
                int bi = ((tab ? eb : ea) << 6) | lane;   // global point idx
                // pack: positive-f32 bits order-isomorphic; ~idx tie->lower
                unsigned long long key =
                    ((unsigned long long)__float_as_uint(bv) << 32) |
                    (unsigned)(~(unsigned)bi);
                WAVE_KEY_MAX(key);   // all lanes now hold the global max
                const int wi = (int)(~(unsigned)(key & 0xFFFFFFFFull));
                cx = px[wi];         // uniform addr -> broadcast LDS reads
                cy = py[wi];
                cz = pz[wi];
                if (lane == 0) {
                    hist[s] = make_float4(__int_as_float(wi), cx, cy, cz);
                    // release orders the hist write before cnt for readers
                    __hip_atomic_store(cnt, s, __ATOMIC_RELEASE,
                                       __HIP_MEMORY_SCOPE_WORKGROUP);
                }
            }
            return;
        }
        if (wv == 1) {
            // ---------------- publisher wave: drains hist ------------------
            for (int chunk = 0; chunk < 16; ++chunk) {
                const int base = chunk * 64;
                const int need = base + 63;   // cnt==s => hist[s] visible
                while (__hip_atomic_load(cnt, __ATOMIC_ACQUIRE,
                                         __HIP_MEMORY_SCOPE_WORKGROUP) < need) {
                    __builtin_amdgcn_s_sleep(32);
                }
                const int e = base + lane;
                float4 h = hist[e];
                const int gi = b * NS + e;
                __hip_atomic_store((unsigned*)&histg[(size_t)gi * 3 + 0],
                                   __float_as_uint(h.y), __ATOMIC_RELAXED,
                                   __HIP_MEMORY_SCOPE_AGENT);
                __hip_atomic_store((unsigned*)&histg[(size_t)gi * 3 + 1],
                                   __float_as_uint(h.z), __ATOMIC_RELAXED,
                                   __HIP_MEMORY_SCOPE_AGENT);
                __hip_atomic_store((unsigned*)&histg[(size_t)gi * 3 + 2],
                                   __float_as_uint(h.w), __ATOMIC_RELAXED,
                                   __HIP_MEMORY_SCOPE_AGENT);
                out_pos[(size_t)gi * 3 + 0] = h.y;
                out_pos[(size_t)gi * 3 + 1] = h.z;
                out_pos[(size_t)gi * 3 + 2] = h.w;
                out_batch[gi] = (float)b;
                asm volatile("s_waitcnt vmcnt(0)" ::: "memory");
                if (lane == 0)
                    __hip_atomic_store(&progress[b << 5], base + 64,
                                       __ATOMIC_RELEASE,
                                       __HIP_MEMORY_SCOPE_AGENT);
            }
            return;
        }
        return;  // waves 2-3 idle
    }

    // ======================= consumer: ball + MFMA conv (R12) ===============
    const int w = blockIdx.x - NB;  // 0..239
    short* h1s = (short*)smem;                      // 8KB
    short* h2s = (short*)(smem + 8192);             // 8KB
    float* cd2 = (float*)(smem + 16384);            // [4][CAP]
    int*   cix = (int*)(smem + 18432);              // [4][CAP]
    float* dpxA = (float*)(smem + 20480);           // [4][64]
    float* dpyA = (float*)(smem + 21504);
    float* dpzA = (float*)(smem + 22528);
    int*   jA   = (int*)(smem + 23552);             // [4][64]
    float* omax = (float*)(smem + 24576);           // [4][128]
    int*   keepW = (int*)(smem + 26624);            // [4]
    const int lg = lane >> 4;
    const int lr = lane & 15;
    // ---- W fragments (bf16) into registers, once per block ----
    bf16x8 w1f[3][4], w2f[2][4], w3f[2][8];
#pragma unroll
    for (int kt = 0; kt < 3; ++kt)
#pragma unroll
        for (int ct = 0; ct < 4; ++ct) {
            bf16x8 f;
#pragma unroll
            for (int i = 0; i < 8; ++i) {
                int k = 32 * kt + 8 * lg + i;
                float v = (k < 67) ? W1[k * 64 + 16 * ct + lr] : 0.f;
                f[i] = f2bf(v);
            }
            w1f[kt][ct] = f;
        }
#pragma unroll
    for (int kt = 0; kt < 2; ++kt)
#pragma unroll
        for (int ct = 0; ct < 4; ++ct) {
            bf16x8 f;
#pragma unroll
            for (int i = 0; i < 8; ++i) {
                int k = 32 * kt + 8 * lg + i;
                f[i] = f2bf(W2[k * 64 + 16 * ct + lr]);
            }
            w2f[kt][ct] = f;
        }
#pragma unroll
    for (int kt = 0; kt < 2; ++kt)
#pragma unroll
        for (int ct = 0; ct < 8; ++ct) {
            bf16x8 f;
#pragma unroll
            for (int i = 0; i < 8; ++i) {
                int k = 32 * kt + 8 * lg + i;
                f[i] = f2bf(W3[k * 128 + 16 * ct + lr]);
            }
            w3f[kt][ct] = f;
        }
    float b1v[4], b2v[4], b3v[8];
#pragma unroll
    for (int ct = 0; ct < 4; ++ct) {
        b1v[ct] = b1[16 * ct + lr];
        b2v[ct] = b2[16 * ct + lr];
    }
#pragma unroll
    for (int ct = 0; ct < 8; ++ct) b3v[ct] = b3[16 * ct + lr];

    for (int c = w; c < NCHUNK; c += NCONS) {
        const int s = c >> 2;
        const int bq = (c & 3) << 2;
        const int bw = bq + wv;
        while (__hip_atomic_load(&progress[bw << 5], __ATOMIC_ACQUIRE,
                                 __HIP_MEMORY_SCOPE_AGENT) <= s) {
            __builtin_amdgcn_s_sleep(16);
        }
        const size_t ho = ((size_t)(bw * NS + s)) * 3;
        const float ccx = __uint_as_float(__hip_atomic_load(
            (const unsigned*)&histg[ho + 0], __ATOMIC_RELAXED,
            __HIP_MEMORY_SCOPE_AGENT));
        const float ccy = __uint_as_float(__hip_atomic_load(
            (const unsigned*)&histg[ho + 1], __ATOMIC_RELAXED,
            __HIP_MEMORY_SCOPE_AGENT));
        const float ccz = __uint_as_float(__hip_atomic_load(
            (const unsigned*)&histg[ho + 2], __ATOMIC_RELAXED,
            __HIP_MEMORY_SCOPE_AGENT));
        // ---- per-wave ball query ----
        int cnt2 = 0;
        const float* pcloud = pos + (size_t)bw * NP * 3;
        for (int it = 0; it < 64; ++it) {
            const int j = it * 64 + lane;
            const float* pp = pcloud + (size_t)j * 3;
            float d2 = dist2e(ccx, ccy, ccz, pp[0], pp[1], pp[2]);
            bool in = (d2 <= 0.01f);  // f32(0.1*0.1)
            unsigned long long m = __ballot(in);
            if (in) {
                int slot = cnt2 + __popcll(m & ((1ull << lane) - 1ull));
                if (slot < CAP) {
                    cd2[wv * CAP + slot] = d2;
                    cix[wv * CAP + slot] = j;
                }
            }
            cnt2 += __popcll(m);
        }
        if (cnt2 > CAP) cnt2 = CAP;
        const int keep = cnt2 <= KN ? cnt2 : KN;
        if (lane == 0) keepW[wv] = keep;
        jA[wv * 64 + lane] = 0;
        if (cnt2 <= KN) {
            if (lane < keep) jA[wv * 64 + lane] = cix[wv * CAP + lane];
        } else {
            // exact K-nearest: rank by (d2, idx) lexicographic (top_k order)
            for (int e = lane; e < cnt2; e += 64) {
                float d = cd2[wv * CAP + e];
                int id = cix[wv * CAP + e];
                int rank = 0;
                for (int q = 0; q < cnt2; ++q) {
                    float dq = cd2[wv * CAP + q];
                    int iq = cix[wv * CAP + q];
                    rank += (dq < d || (dq == d && iq < id)) ? 1 : 0;
                }
                if (rank < KN) jA[wv * 64 + rank] = id;
            }
        }
        {
            int j = jA[wv * 64 + lane];
            const float* pp = pcloud + (size_t)j * 3;
            bool valid = lane < keep;
            dpxA[wv * 64 + lane] = valid ? (pp[0] - ccx) : 0.f;
            dpyA[wv * 64 + lane] = valid ? (pp[1] - ccy) : 0.f;
            dpzA[wv * 64 + lane] = valid ? (pp[2] - ccz) : 0.f;
        }
        __syncthreads();
        // ---- conv for the 4 centers (R10 MFMA path) ----
        for (int cc = 0; cc < 4; ++cc) {
            const int C = keepW[cc];
            const int cen = (bq + cc) * NS + s;
            const int arow = 16 * wv + lr;
            bf16x8 a0, a1, a2;
            {
                const int jrow = (bq + cc) * NP + jA[cc * 64 + arow];
                const float* xr = x + (size_t)jrow * FIN + 8 * lg;
                float4 v0 = *(const float4*)(xr + 0);
                float4 v1 = *(const float4*)(xr + 4);
                float4 v2 = *(const float4*)(xr + 32);
                float4 v3 = *(const float4*)(xr + 36);
                a0[0] = f2bf(v0.x); a0[1] = f2bf(v0.y); a0[2] = f2bf(v0.z); a0[3] = f2bf(v0.w);
                a0[4] = f2bf(v1.x); a0[5] = f2bf(v1.y); a0[6] = f2bf(v1.z); a0[7] = f2bf(v1.w);
                a1[0] = f2bf(v2.x); a1[1] = f2bf(v2.y); a1[2] = f2bf(v2.z); a1[3] = f2bf(v2.w);
                a1[4] = f2bf(v3.x); a1[5] = f2bf(v3.y); a1[6] = f2bf(v3.z); a1[7] = f2bf(v3.w);
                float d0 = (lg == 0) ? dpxA[cc * 64 + arow] : 0.f;
                float d1 = (lg == 0) ? dpyA[cc * 64 + arow] : 0.f;
                float d2v = (lg == 0) ? dpzA[cc * 64 + arow] : 0.f;
                a2[0] = f2bf(d0); a2[1] = f2bf(d1); a2[2] = f2bf(d2v);
                a2[3] = 0; a2[4] = 0; a2[5] = 0; a2[6] = 0; a2[7] = 0;
            }
            {
                f32x4 acc[4];
#pragma unroll
                for (int ct = 0; ct < 4; ++ct) {
                    acc[ct] = (f32x4){b1v[ct], b1v[ct], b1v[ct], b1v[ct]};
                    acc[ct] = __builtin_amdgcn_mfma_f32_16x16x32_bf16(a0, w1f[0][ct], acc[ct], 0, 0, 0);
                    acc[ct] = __builtin_amdgcn_mfma_f32_16x16x32_bf16(a1, w1f[1][ct], acc[ct], 0, 0, 0);
                    acc[ct] = __builtin_amdgcn_mfma_f32_16x16x32_bf16(a2, w1f[2][ct], acc[ct], 0, 0, 0);
                }
#pragma unroll
                for (int ct = 0; ct < 4; ++ct)
#pragma unroll
                    for (int r = 0; r < 4; ++r) {
                        int rw = 16 * wv + 4 * lg + r;
                        int idx = rw * 64 + 16 * ct + lr;
                        h1s[idx ^ ((rw & 7) << 3)] = f2bf(fmaxf(acc[ct][r], 0.f));
                    }
            }
            bf16x8 ha0 = *(bf16x8*)&h1s[(arow * 64 + 0  + 8 * lg) ^ ((arow & 7) << 3)];
            bf16x8 ha1 = *(bf16x8*)&h1s[(arow * 64 + 32 + 8 * lg) ^ ((arow & 7) << 3)];
            {
                f32x4 acc[4];
#pragma unroll
                for (int ct = 0; ct < 4; ++ct) {
                    acc[ct] = (f32x4){b2v[ct], b2v[ct], b2v[ct], b2v[ct]};
                    acc[ct] = __builtin_amdgcn_mfma_f32_16x16x32_bf16(ha0, w2f[0][ct], acc[ct], 0, 0, 0);
                    acc[ct] = __builtin_amdgcn_mfma_f32_16x16x32_bf16(ha1, w2f[1][ct], acc[ct], 0, 0, 0);
                }
#pragma unroll
                for (int ct = 0; ct < 4; ++ct)
#pragma unroll
                    for (int r = 0; r < 4; ++r) {
                        int rw = 16 * wv + 4 * lg + r;
                        int idx = rw * 64 + 16 * ct + lr;
                        h2s[idx ^ ((rw & 7) << 3)] = f2bf(fmaxf(acc[ct][r], 0.f));
                    }
            }
            bf16x8 hb0 = *(bf16x8*)&h2s[(arow * 64 + 0  + 8 * lg) ^ ((arow & 7) << 3)];
            bf16x8 hb1 = *(bf16x8*)&h2s[(arow * 64 + 32 + 8 * lg) ^ ((arow & 7) << 3)];
            {
                f32x4 acc3[8];
#pragma unroll
                for (int ct = 0; ct < 8; ++ct) {
                    acc3[ct] = (f32x4){b3v[ct], b3v[ct], b3v[ct], b3v[ct]};
                    acc3[ct] = __builtin_amdgcn_mfma_f32_16x16x32_bf16(hb0, w3f[0][ct], acc3[ct], 0, 0, 0);
                    acc3[ct] = __builtin_amdgcn_mfma_f32_16x16x32_bf16(hb1, w3f[1][ct], acc3[ct], 0, 0, 0);
                }
#pragma unroll
                for (int ct = 0; ct < 8; ++ct) {
                    float m = -INFINITY;
#pragma unroll
                    for (int r = 0; r < 4; ++r) {
                        int rg = 16 * wv + 4 * lg + r;
                        float v = fmaxf(acc3[ct][r], 0.f);
                        m = (rg < C && v > m) ? v : m;
                    }
                    m = fmaxf(m, __shfl_xor(m, 16, 64));
                    m = fmaxf(m, __shfl_xor(m, 32, 64));
                    if (lg == 0) omax[wv * 128 + 16 * ct + lr] = m;
                }
            }
            __syncthreads();
            if (tid < 128) {
                float m = fmaxf(fmaxf(omax[0 * 128 + tid], omax[1 * 128 + tid]),
                                fmaxf(omax[2 * 128 + tid], omax[3 * 128 + tid]));
                out_feat[(size_t)cen * 128 + tid] = m;
            }
            __syncthreads();
        }
    }
}

extern "C" void kernel_launch(void* const* d_in, const int* in_sizes, int n_in,
                              void* d_out, int out_size, void* d_ws, size_t ws_size,
                              hipStream_t stream) {
    const float* x   = (const float*)d_in[0];
    const float* pos = (const float*)d_in[1];
    const float* W1  = (const float*)d_in[3];
    const float* b1  = (const float*)d_in[4];
    const float* W2  = (const float*)d_in[5];
    const float* b2  = (const float*)d_in[6];
    const float* W3  = (const float*)d_in[7];
    const float* b3  = (const float*)d_in[8];
    float* out = (float*)d_out;
    char* ws = (char*)d_ws;
    int*   progress = (int*)ws;                    // 16 x 128B padded slots
    float* histg    = (float*)(ws + 4096);         // [16][1024][3] = 192KB
    float* out_feat  = out;                        // [16384][128]
    float* out_pos   = out + (size_t)16384 * 128;  // [16384][3]
    float* out_batch = out + (size_t)16384 * 131;  // [16384]
    hipMemsetAsync(ws, 0, 4096, stream);
    fused_kernel<<<256, 256, 0, stream>>>(pos, x, W1, b1, W2, b2, W3, b3,
                                          out_feat, out_pos, out_batch,
                                          histg, progress);
}

// Round 19
// 941.671 us; speedup vs baseline: 1.9375x; 1.9375x over previous
//
#include <hip/hip_runtime.h>
#include <hip/hip_bf16.h>
#include <math.h>

// PointNet++ SAModule: FPS -> ball query -> PointNetConv(MLP, max-agg)
// B=16, N=4096, S=1024, K=64, r=0.1, MLP 67->64->64->128.
// R19 = R17 (best measured, 913.6us) + STREAMING publish: each step, lanes
// 0/1/2 issue the center's 3 histg stores (relaxed agent atomics, no wait --
// next step's barrier drains them); the 64-step publish block shrinks to a
// bare scalar progress release (no burst, no extra barriers). Ordering proof:
// stores for centers < s issued in steps < s, drained by step-s barrier,
// then released. Chain math/selection bit-identical to R17.

#define NB 16
#define NP 4096
#define FIN 64
#define NS 1024
#define KN 64
#define CAP 128
#define NCONS 240
#define NCHUNK 4096

typedef __attribute__((ext_vector_type(8))) short bf16x8;
typedef __attribute__((ext_vector_type(4))) float f32x4;
typedef __attribute__((ext_vector_type(2))) float f32x2;

__device__ __forceinline__ float dist2e(float ax, float ay, float az,
                                        float bx, float by, float bz) {
    float dx = __fsub_rn(ax, bx);
    float dy = __fsub_rn(ay, by);
    float dz = __fsub_rn(az, bz);
    return __fadd_rn(__fadd_rn(__fmul_rn(dx, dx), __fmul_rn(dy, dy)),
                     __fmul_rn(dz, dz));
}

__device__ __forceinline__ short f2bf(float f) {  // RNE fp32 -> bf16 bits
    unsigned u = __float_as_uint(f);
    unsigned r = (u + 0x7FFFu + ((u >> 16) & 1u)) >> 16;
    return (short)r;
}

#define DPP_KEY_MAX(k, CTRL)                                                   \
    do {                                                                       \
        int _lo = (int)(unsigned)((k) & 0xFFFFFFFFull);                        \
        int _hi = (int)(unsigned)((k) >> 32);                                  \
        int _plo = __builtin_amdgcn_update_dpp(_lo, _lo, CTRL, 0xF, 0xF, false);\
        int _phi = __builtin_amdgcn_update_dpp(_hi, _hi, CTRL, 0xF, 0xF, false);\
        unsigned long long _nk =                                               \
            ((unsigned long long)(unsigned)_phi << 32) | (unsigned)_plo;       \
        if (_nk > (k)) (k) = _nk;                                              \
    } while (0)

#define SMEM_BYTES 27648

__global__ __launch_bounds__(256, 1) void fused_kernel(
        const float* __restrict__ pos, const float* __restrict__ x,
        const float* __restrict__ W1, const float* __restrict__ b1,
        const float* __restrict__ W2, const float* __restrict__ b2,
        const float* __restrict__ W3, const float* __restrict__ b3,
        float* __restrict__ out_feat, float* __restrict__ out_pos,
        float* __restrict__ out_batch, float* __restrict__ histg,
        int* __restrict__ progress) {
    __shared__ __align__(16) char smem[SMEM_BYTES];
    const int tid = threadIdx.x;
    const int lane = tid & 63;
    const int wv = tid >> 6;

    if (blockIdx.x < NB) {
        // ============ FPS producer (R17 chain + streaming publish) ==========
        const int b = blockIdx.x;
        float4* hist = (float4*)smem;                       // [1024] 16KB
        float (*bc)[4][8] = (float(*)[4][8])(smem + 16384); // [2][4][8]
        const float* p = pos + (size_t)b * NP * 3;
        f32x2 lx2[8], ly2[8], lz2[8], md2[8];
#pragma unroll
        for (int k = 0; k < 8; ++k) {
#pragma unroll
            for (int e = 0; e < 2; ++e) {
                int j = tid + ((2 * k + e) << 8);
                lx2[k][e] = p[j * 3 + 0];
                ly2[k][e] = p[j * 3 + 1];
                lz2[k][e] = p[j * 3 + 2];
            }
            md2[k] = (f32x2){INFINITY, INFINITY};
        }
        const float c0x = p[0], c0y = p[1], c0z = p[2];
        float cx = c0x, cy = c0y, cz = c0z;
        if (tid == 0) hist[0] = make_float4(0.f, c0x, c0y, c0z);
        if (tid < 3) {  // stream center 0 to histg
            float v = tid == 0 ? c0x : (tid == 1 ? c0y : c0z);
            __hip_atomic_store((unsigned*)&histg[(size_t)(b * NS) * 3 + tid],
                               __float_as_uint(v), __ATOMIC_RELAXED,
                               __HIP_MEMORY_SCOPE_AGENT);
        }
        for (int s = 1; s < NS; ++s) {
            // packed md update (RN per element, no contraction -> bit-exact)
            {
#pragma clang fp contract(off)
                const f32x2 cx2 = (f32x2){cx, cx};
                const f32x2 cy2 = (f32x2){cy, cy};
                const f32x2 cz2 = (f32x2){cz, cz};
#pragma unroll
                for (int k = 0; k < 8; ++k) {
                    f32x2 dx = lx2[k] - cx2;
                    f32x2 dy = ly2[k] - cy2;
                    f32x2 dz = lz2[k] - cz2;
                    f32x2 d = (dx * dx + dy * dy) + dz * dz;
                    f32x2 m = md2[k];
                    m[0] = d[0] < m[0] ? d[0] : m[0];  // jnp.minimum (exact)
                    m[1] = d[1] < m[1] ? d[1] : m[1];
                    md2[k] = m;
                }
            }
            // scalar argmax scan, ascending index, strict > (np.argmax
            // first-occurrence), with xyz carry
            float bv = -1.0f;
            int bi = 0;
            float wx = 0.f, wy = 0.f, wz = 0.f;
#pragma unroll
            for (int k = 0; k < 8; ++k) {
#pragma unroll
                for (int e = 0; e < 2; ++e) {
                    float m = md2[k][e];
                    bool take = (m > bv);
                    bv = take ? m : bv;
                    bi = take ? (tid + ((2 * k + e) << 8)) : bi;
                    wx = take ? lx2[k][e] : wx;
                    wy = take ? ly2[k][e] : wy;
                    wz = take ? lz2[k][e] : wz;
                }
            }
            // pack: positive-f32 bits order-isomorphic; ~idx => tie->lower idx
            unsigned long long key =
                ((unsigned long long)__float_as_uint(bv) << 32) |
                (unsigned)(~(unsigned)bi);
            const unsigned long long my = key;
            DPP_KEY_MAX(key, 0x111);
            DPP_KEY_MAX(key, 0x112);
            DPP_KEY_MAX(key, 0x114);
            DPP_KEY_MAX(key, 0x118);
            DPP_KEY_MAX(key, 0x142);
            DPP_KEY_MAX(key, 0x143);
            const unsigned kwlo = (unsigned)__builtin_amdgcn_readlane(
                (int)(unsigned)(key & 0xFFFFFFFFull), 63);
            const unsigned kwhi = (unsigned)__builtin_amdgcn_readlane(
                (int)(unsigned)(key >> 32), 63);
            const unsigned long long kw =
                ((unsigned long long)kwhi << 32) | kwlo;
            const int buf = s & 1;
            if (my == kw) {            // unique winner lane (idx in key)
                bc[buf][wv][0] = __uint_as_float(kwlo);
                bc[buf][wv][1] = __uint_as_float(kwhi);
                bc[buf][wv][2] = wx;
                bc[buf][wv][3] = wy;
                bc[buf][wv][4] = wz;
            }
            __syncthreads();
            // publish: stores for centers < s were issued in steps < s and
            // drained by the barrier above -> bare scalar release suffices
            if ((s & 63) == 0 && tid == 0)
                __hip_atomic_store(&progress[b << 5], s, __ATOMIC_RELEASE,
                                   __HIP_MEMORY_SCOPE_AGENT);
            // all lanes: select best of the 4 wave candidates
            unsigned long long bk;
            float bx, by, bz;
            {
                float4 e = *(const float4*)&bc[buf][0][0];
                bk = ((unsigned long long)__float_as_uint(e.y) << 32) |
                     __float_as_uint(e.x);
                bx = e.z; by = e.w; bz = bc[buf][0][4];
            }
#pragma unroll
            for (int w = 1; w < 4; ++w) {
                float4 e = *(const float4*)&bc[buf][w][0];
                unsigned long long k2 =
                    ((unsigned long long)__float_as_uint(e.y) << 32) |
                    __float_as_uint(e.x);
                float z2 = bc[buf][w][4];
                bool take = (k2 > bk);
                bk = take ? k2 : bk;
                bx = take ? e.z : bx;
                by = take ? e.w : by;
                bz = take ? z2 : bz;
            }
            const int cur = (int)(~(unsigned)(bk & 0xFFFFFFFFull));
            cx = bx; cy = by; cz = bz;
            if (tid == 0)
                hist[s] = make_float4(__int_as_float(cur), bx, by, bz);
            if (tid < 3) {  // stream this center to histg (fire-and-forget)
                float v = tid == 0 ? bx : (tid == 1 ? by : bz);
                __hip_atomic_store(
                    (unsigned*)&histg[((size_t)(b * NS + s)) * 3 + tid],
                    __float_as_uint(v), __ATOMIC_RELAXED,
                    __HIP_MEMORY_SCOPE_AGENT);
            }
        }
        __syncthreads();   // drains the last streamed stores
        if (tid == 0)
            __hip_atomic_store(&progress[b << 5], NS, __ATOMIC_RELEASE,
                               __HIP_MEMORY_SCOPE_AGENT);
        for (int s = tid; s < NS; s += 256) {
            float4 e = hist[s];
            out_pos[(size_t)(b * NS + s) * 3 + 0] = e.y;
            out_pos[(size_t)(b * NS + s) * 3 + 1] = e.z;
            out_pos[(size_t)(b * NS + s) * 3 + 2] = e.w;
            out_batch[b * NS + s] = (float)b;
        }
        return;
    }

    // ======================= consumer: ball + MFMA conv (R12) ===============
    const int w = blockIdx.x - NB;  // 0..239
    short* h1s = (short*)smem;                      // 8KB
    short* h2s = (short*)(smem + 8192);             // 8KB
    float* cd2 = (float*)(smem + 16384);            // [4][CAP]
    int*   cix = (int*)(smem + 18432);              // [4][CAP]
    float* dpxA = (float*)(smem + 20480);           // [4][64]
    float* dpyA = (float*)(smem + 21504);
    float* dpzA = (float*)(smem + 22528);
    int*   jA   = (int*)(smem + 23552);             // [4][64]
    float* omax = (float*)(smem + 24576);           // [4][128]
    int*   keepW = (int*)(smem + 26624);            // [4]
    const int lg = lane >> 4;
    const int lr = lane & 15;
    // ---- W fragments (bf16) into registers, once per block ----
    bf16x8 w1f[3][4], w2f[2][4], w3f[2][8];
#pragma unroll
    for (int kt = 0; kt < 3; ++kt)
#pragma unroll
        for (int ct = 0; ct < 4; ++ct) {
            bf16x8 f;
#pragma unroll
            for (int i = 0; i < 8; ++i) {
                int k = 32 * kt + 8 * lg + i;
                float v = (k < 67) ? W1[k * 64 + 16 * ct + lr] : 0.f;
                f[i] = f2bf(v);
            }
            w1f[kt][ct] = f;
        }
#pragma unroll
    for (int kt = 0; kt < 2; ++kt)
#pragma unroll
        for (int ct = 0; ct < 4; ++ct) {
            bf16x8 f;
#pragma unroll
            for (int i = 0; i < 8; ++i) {
                int k = 32 * kt + 8 * lg + i;
                f[i] = f2bf(W2[k * 64 + 16 * ct + lr]);
            }
            w2f[kt][ct] = f;
        }
#pragma unroll
    for (int kt = 0; kt < 2; ++kt)
#pragma unroll
        for (int ct = 0; ct < 8; ++ct) {
            bf16x8 f;
#pragma unroll
            for (int i = 0; i < 8; ++i) {
                int k = 32 * kt + 8 * lg + i;
                f[i] = f2bf(W3[k * 128 + 16 * ct + lr]);
            }
            w3f[kt][ct] = f;
        }
    float b1v[4], b2v[4], b3v[8];
#pragma unroll
    for (int ct = 0; ct < 4; ++ct) {
        b1v[ct] = b1[16 * ct + lr];
        b2v[ct] = b2[16 * ct + lr];
    }
#pragma unroll
    for (int ct = 0; ct < 8; ++ct) b3v[ct] = b3[16 * ct + lr];

    for (int c = w; c < NCHUNK; c += NCONS) {
        const int s = c >> 2;
        const int bq = (c & 3) << 2;
        const int bw = bq + wv;
        while (__hip_atomic_load(&progress[bw << 5], __ATOMIC_ACQUIRE,
                                 __HIP_MEMORY_SCOPE_AGENT) <= s) {
            __builtin_amdgcn_s_sleep(16);
        }
        const size_t ho = ((size_t)(bw * NS + s)) * 3;
        const float ccx = __uint_as_float(__hip_atomic_load(
            (const unsigned*)&histg[ho + 0], __ATOMIC_RELAXED,
            __HIP_MEMORY_SCOPE_AGENT));
        const float ccy = __uint_as_float(__hip_atomic_load(
            (const unsigned*)&histg[ho + 1], __ATOMIC_RELAXED,
            __HIP_MEMORY_SCOPE_AGENT));
        const float ccz = __uint_as_float(__hip_atomic_load(
            (const unsigned*)&histg[ho + 2], __ATOMIC_RELAXED,
            __HIP_MEMORY_SCOPE_AGENT));
        // ---- per-wave ball query ----
        int cnt = 0;
        const float* pcloud = pos + (size_t)bw * NP * 3;
        for (int it = 0; it < 64; ++it) {
            const int j = it * 64 + lane;
            const float* pp = pcloud + (size_t)j * 3;
            float d2 = dist2e(ccx, ccy, ccz, pp[0], pp[1], pp[2]);
            bool in = (d2 <= 0.01f);  // f32(0.1*0.1)
            unsigned long long m = __ballot(in);
            if (in) {
                int slot = cnt + __popcll(m & ((1ull << lane) - 1ull));
                if (slot < CAP) {
                    cd2[wv * CAP + slot] = d2;
                    cix[wv * CAP + slot] = j;
                }
            }
            cnt += __popcll(m);
        }
        if (cnt > CAP) cnt = CAP;
        const int keep = cnt <= KN ? cnt : KN;
        if (lane == 0) keepW[wv] = keep;
        jA[wv * 64 + lane] = 0;
        if (cnt <= KN) {
            if (lane < keep) jA[wv * 64 + lane] = cix[wv * CAP + lane];
        } else {
            // exact K-nearest: rank by (d2, idx) lexicographic (top_k order)
            for (int e = lane; e < cnt; e += 64) {
                float d = cd2[wv * CAP + e];
                int id = cix[wv * CAP + e];
                int rank = 0;
                for (int q = 0; q < cnt; ++q) {
                    float dq = cd2[wv * CAP + q];
                    int iq = cix[wv * CAP + q];
                    rank += (dq < d || (dq == d && iq < id)) ? 1 : 0;
                }
                if (rank < KN) jA[wv * 64 + rank] = id;
            }
        }
        {
            int j = jA[wv * 64 + lane];
            const float* pp = pcloud + (size_t)j * 3;
            bool valid = lane < keep;
            dpxA[wv * 64 + lane] = valid ? (pp[0] - ccx) : 0.f;
            dpyA[wv * 64 + lane] = valid ? (pp[1] - ccy) : 0.f;
            dpzA[wv * 64 + lane] = valid ? (pp[2] - ccz) : 0.f;
        }
        __syncthreads();
        // ---- conv for the 4 centers (R10 MFMA path) ----
        for (int cc = 0; cc < 4; ++cc) {
            const int C = keepW[cc];
            const int cen = (bq + cc) * NS + s;
            const int arow = 16 * wv + lr;
            bf16x8 a0, a1, a2;
            {
                const int jrow = (bq + cc) * NP + jA[cc * 64 + arow];
                const float* xr = x + (size_t)jrow * FIN + 8 * lg;
                float4 v0 = *(const float4*)(xr + 0);
                float4 v1 = *(const float4*)(xr + 4);
                float4 v2 = *(const float4*)(xr + 32);
                float4 v3 = *(const float4*)(xr + 36);
                a0[0] = f2bf(v0.x); a0[1] = f2bf(v0.y); a0[2] = f2bf(v0.z); a0[3] = f2bf(v0.w);
                a0[4] = f2bf(v1.x); a0[5] = f2bf(v1.y); a0[6] = f2bf(v1.z); a0[7] = f2bf(v1.w);
                a1[0] = f2bf(v2.x); a1[1] = f2bf(v2.y); a1[2] = f2bf(v2.z); a1[3] = f2bf(v2.w);
                a1[4] = f2bf(v3.x); a1[5] = f2bf(v3.y); a1[6] = f2bf(v3.z); a1[7] = f2bf(v3.w);
                float d0 = (lg == 0) ? dpxA[cc * 64 + arow] : 0.f;
                float d1 = (lg == 0) ? dpyA[cc * 64 + arow] : 0.f;
                float d2v = (lg == 0) ? dpzA[cc * 64 + arow] : 0.f;
                a2[0] = f2bf(d0); a2[1] = f2bf(d1); a2[2] = f2bf(d2v);
                a2[3] = 0; a2[4] = 0; a2[5] = 0; a2[6] = 0; a2[7] = 0;
            }
            {
                f32x4 acc[4];
#pragma unroll
                for (int ct = 0; ct < 4; ++ct) {
                    acc[ct] = (f32x4){b1v[ct], b1v[ct], b1v[ct], b1v[ct]};
                    acc[ct] = __builtin_amdgcn_mfma_f32_16x16x32_bf16(a0, w1f[0][ct], acc[ct], 0, 0, 0);
                    acc[ct] = __builtin_amdgcn_mfma_f32_16x16x32_bf16(a1, w1f[1][ct], acc[ct], 0, 0, 0);
                    acc[ct] = __builtin_amdgcn_mfma_f32_16x16x32_bf16(a2, w1f[2][ct], acc[ct], 0, 0, 0);
                }
#pragma unroll
                for (int ct = 0; ct < 4; ++ct)
#pragma unroll
                    for (int r = 0; r < 4; ++r) {
                        int rw = 16 * wv + 4 * lg + r;
                        int idx = rw * 64 + 16 * ct + lr;
                        h1s[idx ^ ((rw & 7) << 3)] = f2bf(fmaxf(acc[ct][r], 0.f));
                    }
            }
            bf16x8 ha0 = *(bf16x8*)&h1s[(arow * 64 + 0  + 8 * lg) ^ ((arow & 7) << 3)];
            bf16x8 ha1 = *(bf16x8*)&h1s[(arow * 64 + 32 + 8 * lg) ^ ((arow & 7) << 3)];
            {
                f32x4 acc[4];
#pragma unroll
                for (int ct = 0; ct < 4; ++ct) {
                    acc[ct] = (f32x4){b2v[ct], b2v[ct], b2v[ct], b2v[ct]};
                    acc[ct] = __builtin_amdgcn_mfma_f32_16x16x32_bf16(ha0, w2f[0][ct], acc[ct], 0, 0, 0);
                    acc[ct] = __builtin_amdgcn_mfma_f32_16x16x32_bf16(ha1, w2f[1][ct], acc[ct], 0, 0, 0);
                }
#pragma unroll
                for (int ct = 0; ct < 4; ++ct)
#pragma unroll
                    for (int r = 0; r < 4; ++r) {
                        int rw = 16 * wv + 4 * lg + r;
                        int idx = rw * 64 + 16 * ct + lr;
                        h2s[idx ^ ((rw & 7) << 3)] = f2bf(fmaxf(acc[ct][r], 0.f));
                    }
            }
            bf16x8 hb0 = *(bf16x8*)&h2s[(arow * 64 + 0  + 8 * lg) ^ ((arow & 7) << 3)];
            bf16x8 hb1 = *(bf16x8*)&h2s[(arow * 64 + 32 + 8 * lg) ^ ((arow & 7) << 3)];
            {
                f32x4 acc3[8];
#pragma unroll
                for (int ct = 0; ct < 8; ++ct) {
                    acc3[ct] = (f32x4){b3v[ct], b3v[ct], b3v[ct], b3v[ct]};
                    acc3[ct] = __builtin_amdgcn_mfma_f32_16x16x32_bf16(hb0, w3f[0][ct], acc3[ct], 0, 0, 0);
                    acc3[ct] = __builtin_amdgcn_mfma_f32_16x16x32_bf16(hb1, w3f[1][ct], acc3[ct], 0, 0, 0);
                }
#pragma unroll
                for (int ct = 0; ct < 8; ++ct) {
                    float m = -INFINITY;
#pragma unroll
                    for (int r = 0; r < 4; ++r) {
                        int rg = 16 * wv + 4 * lg + r;
                        float v = fmaxf(acc3[ct][r], 0.f);
                        m = (rg < C && v > m) ? v : m;
                    }
                    m = fmaxf(m, __shfl_xor(m, 16, 64));
                    m = fmaxf(m, __shfl_xor(m, 32, 64));
                    if (lg == 0) omax[wv * 128 + 16 * ct + lr] = m;
                }
            }
            __syncthreads();
            if (tid < 128) {
                float m = fmaxf(fmaxf(omax[0 * 128 + tid], omax[1 * 128 + tid]),
                                fmaxf(omax[2 * 128 + tid], omax[3 * 128 + tid]));
                out_feat[(size_t)cen * 128 + tid] = m;
            }
            __syncthreads();
        }
    }
}

extern "C" void kernel_launch(void* const* d_in, const int* in_sizes, int n_in,
                              void* d_out, int out_size, void* d_ws, size_t ws_size,
                              hipStream_t stream) {
    const float* x   = (const float*)d_in[0];
    const float* pos = (const float*)d_in[1];
    const float* W1  = (const float*)d_in[3];
    const float* b1  = (const float*)d_in[4];
    const float* W2  = (const float*)d_in[5];
    const float* b2  = (const float*)d_in[6];
    const float* W3  = (const float*)d_in[7];
    const float* b3  = (const float*)d_in[8];
    float* out = (float*)d_out;
    char* ws = (char*)d_ws;
    int*   progress = (int*)ws;                    // 16 x 128B padded slots
    float* histg    = (float*)(ws + 4096);         // [16][1024][3] = 192KB
    float* out_feat  = out;                        // [16384][128]
    float* out_pos   = out + (size_t)16384 * 128;  // [16384][3]
    float* out_batch = out + (size_t)16384 * 131;  // [16384]
    hipMemsetAsync(ws, 0, 4096, stream);
    fused_kernel<<<256, 256, 0, stream>>>(pos, x, W1, b1, W2, b2, W3, b3,
                                          out_feat, out_pos, out_batch,
                                          histg, progress);
}

// Round 20
// 915.578 us; speedup vs baseline: 1.9927x; 1.0285x over previous
//
#include <hip/hip_runtime.h>
#include <hip/hip_bf16.h>
#include <math.h>

// PointNet++ SAModule: FPS -> ball query -> PointNetConv(MLP, max-agg)
// B=16, N=4096, S=1024, K=64, r=0.1, MLP 67->64->64->128.
// R20 = R17 verbatim (best measured: 913.6us; R19's streaming publish
// regressed +28us and is reverted). Producer: 4-wave chain, packed-f32 local
// update (RN, no contraction -> bit-exact), scalar ascending argmax scan,
// key-only 6-DPP u64 ladder + readlane broadcast, winner-writes-bc, ONE
// barrier/step, 64-step burst publish + padded progress release. Consumers:
// per-wave ball query + R10 MFMA conv, hidden behind the chain.
// Selection decisions bit-exact vs numpy; conv in bf16 (absmax 0.0156 << 0.3).

#define NB 16
#define NP 4096
#define FIN 64
#define NS 1024
#define KN 64
#define CAP 128
#define NCONS 240
#define NCHUNK 4096

typedef __attribute__((ext_vector_type(8))) short bf16x8;
typedef __attribute__((ext_vector_type(4))) float f32x4;
typedef __attribute__((ext_vector_type(2))) float f32x2;

__device__ __forceinline__ float dist2e(float ax, float ay, float az,
                                        float bx, float by, float bz) {
    float dx = __fsub_rn(ax, bx);
    float dy = __fsub_rn(ay, by);
    float dz = __fsub_rn(az, bz);
    return __fadd_rn(__fadd_rn(__fmul_rn(dx, dx), __fmul_rn(dy, dy)),
                     __fmul_rn(dz, dz));
}

__device__ __forceinline__ short f2bf(float f) {  // RNE fp32 -> bf16 bits
    unsigned u = __float_as_uint(f);
    unsigned r = (u + 0x7FFFu + ((u >> 16) & 1u)) >> 16;
    return (short)r;
}

#define DPP_KEY_MAX(k, CTRL)                                                   \
    do {                                                                       \
        int _lo = (int)(unsigned)((k) & 0xFFFFFFFFull);                        \
        int _hi = (int)(unsigned)((k) >> 32);                                  \
        int _plo = __builtin_amdgcn_update_dpp(_lo, _lo, CTRL, 0xF, 0xF, false);\
        int _phi = __builtin_amdgcn_update_dpp(_hi, _hi, CTRL, 0xF, 0xF, false);\
        unsigned long long _nk =                                               \
            ((unsigned long long)(unsigned)_phi << 32) | (unsigned)_plo;       \
        if (_nk > (k)) (k) = _nk;                                              \
    } while (0)

#define SMEM_BYTES 27648

__global__ __launch_bounds__(256, 1) void fused_kernel(
        const float* __restrict__ pos, const float* __restrict__ x,
        const float* __restrict__ W1, const float* __restrict__ b1,
        const float* __restrict__ W2, const float* __restrict__ b2,
        const float* __restrict__ W3, const float* __restrict__ b3,
        float* __restrict__ out_feat, float* __restrict__ out_pos,
        float* __restrict__ out_batch, float* __restrict__ histg,
        int* __restrict__ progress) {
    __shared__ __align__(16) char smem[SMEM_BYTES];
    const int tid = threadIdx.x;
    const int lane = tid & 63;
    const int wv = tid >> 6;

    if (blockIdx.x < NB) {
        // =================== FPS producer (R12 + packed local) ==============
        const int b = blockIdx.x;
        float4* hist = (float4*)smem;                       // [1024] 16KB
        float (*bc)[4][8] = (float(*)[4][8])(smem + 16384); // [2][4][8]
        const float* p = pos + (size_t)b * NP * 3;
        f32x2 lx2[8], ly2[8], lz2[8], md2[8];
#pragma unroll
        for (int k = 0; k < 8; ++k) {
#pragma unroll
            for (int e = 0; e < 2; ++e) {
                int j = tid + ((2 * k + e) << 8);
                lx2[k][e] = p[j * 3 + 0];
                ly2[k][e] = p[j * 3 + 1];
                lz2[k][e] = p[j * 3 + 2];
            }
            md2[k] = (f32x2){INFINITY, INFINITY};
        }
        const float c0x = p[0], c0y = p[1], c0z = p[2];
        float cx = c0x, cy = c0y, cz = c0z;
        if (tid == 0) hist[0] = make_float4(0.f, c0x, c0y, c0z);
        for (int s = 1; s < NS; ++s) {
            // packed md update: v_pk_add/mul (IEEE RN per element, no fma
            // contraction) -> identical bits to scalar __f*_rn sequence
            {
#pragma clang fp contract(off)
                const f32x2 cx2 = (f32x2){cx, cx};
                const f32x2 cy2 = (f32x2){cy, cy};
                const f32x2 cz2 = (f32x2){cz, cz};
#pragma unroll
                for (int k = 0; k < 8; ++k) {
                    f32x2 dx = lx2[k] - cx2;
                    f32x2 dy = ly2[k] - cy2;
                    f32x2 dz = lz2[k] - cz2;
                    f32x2 d = (dx * dx + dy * dy) + dz * dz;
                    f32x2 m = md2[k];
                    m[0] = d[0] < m[0] ? d[0] : m[0];  // jnp.minimum (exact)
                    m[1] = d[1] < m[1] ? d[1] : m[1];
                    md2[k] = m;
                }
            }
            // scalar argmax scan, ascending index, strict > (= np.argmax
            // first-occurrence), with xyz carry
            float bv = -1.0f;
            int bi = 0;
            float wx = 0.f, wy = 0.f, wz = 0.f;
#pragma unroll
            for (int k = 0; k < 8; ++k) {
#pragma unroll
                for (int e = 0; e < 2; ++e) {
                    float m = md2[k][e];
                    bool take = (m > bv);
                    bv = take ? m : bv;
                    bi = take ? (tid + ((2 * k + e) << 8)) : bi;
                    wx = take ? lx2[k][e] : wx;
                    wy = take ? ly2[k][e] : wy;
                    wz = take ? lz2[k][e] : wz;
                }
            }
            // pack: positive-f32 bits order-isomorphic; ~idx => tie->lower idx
            unsigned long long key =
                ((unsigned long long)__float_as_uint(bv) << 32) |
                (unsigned)(~(unsigned)bi);
            const unsigned long long my = key;
            DPP_KEY_MAX(key, 0x111);
            DPP_KEY_MAX(key, 0x112);
            DPP_KEY_MAX(key, 0x114);
            DPP_KEY_MAX(key, 0x118);
            DPP_KEY_MAX(key, 0x142);
            DPP_KEY_MAX(key, 0x143);
            const unsigned kwlo = (unsigned)__builtin_amdgcn_readlane(
                (int)(unsigned)(key & 0xFFFFFFFFull), 63);
            const unsigned kwhi = (unsigned)__builtin_amdgcn_readlane(
                (int)(unsigned)(key >> 32), 63);
            const unsigned long long kw =
                ((unsigned long long)kwhi << 32) | kwlo;
            const int buf = s & 1;
            if (my == kw) {            // unique winner lane (idx in key)
                bc[buf][wv][0] = __uint_as_float(kwlo);
                bc[buf][wv][1] = __uint_as_float(kwhi);
                bc[buf][wv][2] = wx;
                bc[buf][wv][3] = wy;
                bc[buf][wv][4] = wz;
            }
            __syncthreads();
            if ((s & 63) == 0) {   // publish centers [s-64, s)
                const int base = s - 64;
                if (tid < 192) {
                    int cc = tid / 3, comp = tid % 3;
                    float4 h = hist[base + cc];
                    float v = comp == 0 ? h.y : (comp == 1 ? h.z : h.w);
                    __hip_atomic_store(
                        (unsigned*)&histg[((size_t)(b * NS + base + cc)) * 3 + comp],
                        __float_as_uint(v), __ATOMIC_RELAXED,
                        __HIP_MEMORY_SCOPE_AGENT);
                }
                __syncthreads();   // drain stores before release
                if (tid == 0)
                    __hip_atomic_store(&progress[b << 5], s, __ATOMIC_RELEASE,
                                       __HIP_MEMORY_SCOPE_AGENT);
            }
            // all lanes: select best of the 4 wave candidates
            unsigned long long bk;
            float bx, by, bz;
            {
                float4 e = *(const float4*)&bc[buf][0][0];
                bk = ((unsigned long long)__float_as_uint(e.y) << 32) |
                     __float_as_uint(e.x);
                bx = e.z; by = e.w; bz = bc[buf][0][4];
            }
#pragma unroll
            for (int w = 1; w < 4; ++w) {
                float4 e = *(const float4*)&bc[buf][w][0];
                unsigned long long k2 =
                    ((unsigned long long)__float_as_uint(e.y) << 32) |
                    __float_as_uint(e.x);
                float z2 = bc[buf][w][4];
                bool take = (k2 > bk);
                bk = take ? k2 : bk;
                bx = take ? e.z : bx;
                by = take ? e.w : by;
                bz = take ? z2 : bz;
            }
            const int cur = (int)(~(unsigned)(bk & 0xFFFFFFFFull));
            cx = bx; cy = by; cz = bz;
            if (tid == 0)
                hist[s] = make_float4(__int_as_float(cur), bx, by, bz);
        }
        __syncthreads();
        // final publish [960,1024) + output drain
        if (tid < 192) {
            int cc = tid / 3, comp = tid % 3;
            float4 h = hist[960 + cc];
            float v = comp == 0 ? h.y : (comp == 1 ? h.z : h.w);
            __hip_atomic_store(
                (unsigned*)&histg[((size_t)(b * NS + 960 + cc)) * 3 + comp],
                __float_as_uint(v), __ATOMIC_RELAXED, __HIP_MEMORY_SCOPE_AGENT);
        }
        __syncthreads();
        if (tid == 0)
            __hip_atomic_store(&progress[b << 5], NS, __ATOMIC_RELEASE,
                               __HIP_MEMORY_SCOPE_AGENT);
        for (int s = tid; s < NS; s += 256) {
            float4 e = hist[s];
            out_pos[(size_t)(b * NS + s) * 3 + 0] = e.y;
            out_pos[(size_t)(b * NS + s) * 3 + 1] = e.z;
            out_pos[(size_t)(b * NS + s) * 3 + 2] = e.w;
            out_batch[b * NS + s] = (float)b;
        }
        return;
    }

    // ======================= consumer: ball + MFMA conv (R12) ===============
    const int w = blockIdx.x - NB;  // 0..239
    short* h1s = (short*)smem;                      // 8KB
    short* h2s = (short*)(smem + 8192);             // 8KB
    float* cd2 = (float*)(smem + 16384);            // [4][CAP]
    int*   cix = (int*)(smem + 18432);              // [4][CAP]
    float* dpxA = (float*)(smem + 20480);           // [4][64]
    float* dpyA = (float*)(smem + 21504);
    float* dpzA = (float*)(smem + 22528);
    int*   jA   = (int*)(smem + 23552);             // [4][64]
    float* omax = (float*)(smem + 24576);           // [4][128]
    int*   keepW = (int*)(smem + 26624);            // [4]
    const int lg = lane >> 4;
    const int lr = lane & 15;
    // ---- W fragments (bf16) into registers, once per block ----
    bf16x8 w1f[3][4], w2f[2][4], w3f[2][8];
#pragma unroll
    for (int kt = 0; kt < 3; ++kt)
#pragma unroll
        for (int ct = 0; ct < 4; ++ct) {
            bf16x8 f;
#pragma unroll
            for (int i = 0; i < 8; ++i) {
                int k = 32 * kt + 8 * lg + i;
                float v = (k < 67) ? W1[k * 64 + 16 * ct + lr] : 0.f;
                f[i] = f2bf(v);
            }
            w1f[kt][ct] = f;
        }
#pragma unroll
    for (int kt = 0; kt < 2; ++kt)
#pragma unroll
        for (int ct = 0; ct < 4; ++ct) {
            bf16x8 f;
#pragma unroll
            for (int i = 0; i < 8; ++i) {
                int k = 32 * kt + 8 * lg + i;
                f[i] = f2bf(W2[k * 64 + 16 * ct + lr]);
            }
            w2f[kt][ct] = f;
        }
#pragma unroll
    for (int kt = 0; kt < 2; ++kt)
#pragma unroll
        for (int ct = 0; ct < 8; ++ct) {
            bf16x8 f;
#pragma unroll
            for (int i = 0; i < 8; ++i) {
                int k = 32 * kt + 8 * lg + i;
                f[i] = f2bf(W3[k * 128 + 16 * ct + lr]);
            }
            w3f[kt][ct] = f;
        }
    float b1v[4], b2v[4], b3v[8];
#pragma unroll
    for (int ct = 0; ct < 4; ++ct) {
        b1v[ct] = b1[16 * ct + lr];
        b2v[ct] = b2[16 * ct + lr];
    }
#pragma unroll
    for (int ct = 0; ct < 8; ++ct) b3v[ct] = b3[16 * ct + lr];

    for (int c = w; c < NCHUNK; c += NCONS) {
        const int s = c >> 2;
        const int bq = (c & 3) << 2;
        const int bw = bq + wv;
        while (__hip_atomic_load(&progress[bw << 5], __ATOMIC_ACQUIRE,
                                 __HIP_MEMORY_SCOPE_AGENT) <= s) {
            __builtin_amdgcn_s_sleep(16);
        }
        const size_t ho = ((size_t)(bw * NS + s)) * 3;
        const float ccx = __uint_as_float(__hip_atomic_load(
            (const unsigned*)&histg[ho + 0], __ATOMIC_RELAXED,
            __HIP_MEMORY_SCOPE_AGENT));
        const float ccy = __uint_as_float(__hip_atomic_load(
            (const unsigned*)&histg[ho + 1], __ATOMIC_RELAXED,
            __HIP_MEMORY_SCOPE_AGENT));
        const float ccz = __uint_as_float(__hip_atomic_load(
            (const unsigned*)&histg[ho + 2], __ATOMIC_RELAXED,
            __HIP_MEMORY_SCOPE_AGENT));
        // ---- per-wave ball query ----
        int cnt = 0;
        const float* pcloud = pos + (size_t)bw * NP * 3;
        for (int it = 0; it < 64; ++it) {
            const int j = it * 64 + lane;
            const float* pp = pcloud + (size_t)j * 3;
            float d2 = dist2e(ccx, ccy, ccz, pp[0], pp[1], pp[2]);
            bool in = (d2 <= 0.01f);  // f32(0.1*0.1)
            unsigned long long m = __ballot(in);
            if (in) {
                int slot = cnt + __popcll(m & ((1ull << lane) - 1ull));
                if (slot < CAP) {
                    cd2[wv * CAP + slot] = d2;
                    cix[wv * CAP + slot] = j;
                }
            }
            cnt += __popcll(m);
        }
        if (cnt > CAP) cnt = CAP;
        const int keep = cnt <= KN ? cnt : KN;
        if (lane == 0) keepW[wv] = keep;
        jA[wv * 64 + lane] = 0;
        if (cnt <= KN) {
            if (lane < keep) jA[wv * 64 + lane] = cix[wv * CAP + lane];
        } else {
            // exact K-nearest: rank by (d2, idx) lexicographic (top_k order)
            for (int e = lane; e < cnt; e += 64) {
                float d = cd2[wv * CAP + e];
                int id = cix[wv * CAP + e];
                int rank = 0;
                for (int q = 0; q < cnt; ++q) {
                    float dq = cd2[wv * CAP + q];
                    int iq = cix[wv * CAP + q];
                    rank += (dq < d || (dq == d && iq < id)) ? 1 : 0;
                }
                if (rank < KN) jA[wv * 64 + rank] = id;
            }
        }
        {
            int j = jA[wv * 64 + lane];
            const float* pp = pcloud + (size_t)j * 3;
            bool valid = lane < keep;
            dpxA[wv * 64 + lane] = valid ? (pp[0] - ccx) : 0.f;
            dpyA[wv * 64 + lane] = valid ? (pp[1] - ccy) : 0.f;
            dpzA[wv * 64 + lane] = valid ? (pp[2] - ccz) : 0.f;
        }
        __syncthreads();
        // ---- conv for the 4 centers (R10 MFMA path) ----
        for (int cc = 0; cc < 4; ++cc) {
            const int C = keepW[cc];
            const int cen = (bq + cc) * NS + s;
            const int arow = 16 * wv + lr;
            bf16x8 a0, a1, a2;
            {
                const int jrow = (bq + cc) * NP + jA[cc * 64 + arow];
                const float* xr = x + (size_t)jrow * FIN + 8 * lg;
                float4 v0 = *(const float4*)(xr + 0);
                float4 v1 = *(const float4*)(xr + 4);
                float4 v2 = *(const float4*)(xr + 32);
                float4 v3 = *(const float4*)(xr + 36);
                a0[0] = f2bf(v0.x); a0[1] = f2bf(v0.y); a0[2] = f2bf(v0.z); a0[3] = f2bf(v0.w);
                a0[4] = f2bf(v1.x); a0[5] = f2bf(v1.y); a0[6] = f2bf(v1.z); a0[7] = f2bf(v1.w);
                a1[0] = f2bf(v2.x); a1[1] = f2bf(v2.y); a1[2] = f2bf(v2.z); a1[3] = f2bf(v2.w);
                a1[4] = f2bf(v3.x); a1[5] = f2bf(v3.y); a1[6] = f2bf(v3.z); a1[7] = f2bf(v3.w);
                float d0 = (lg == 0) ? dpxA[cc * 64 + arow] : 0.f;
                float d1 = (lg == 0) ? dpyA[cc * 64 + arow] : 0.f;
                float d2v = (lg == 0) ? dpzA[cc * 64 + arow] : 0.f;
                a2[0] = f2bf(d0); a2[1] = f2bf(d1); a2[2] = f2bf(d2v);
                a2[3] = 0; a2[4] = 0; a2[5] = 0; a2[6] = 0; a2[7] = 0;
            }
            {
                f32x4 acc[4];
#pragma unroll
                for (int ct = 0; ct < 4; ++ct) {
                    acc[ct] = (f32x4){b1v[ct], b1v[ct], b1v[ct], b1v[ct]};
                    acc[ct] = __builtin_amdgcn_mfma_f32_16x16x32_bf16(a0, w1f[0][ct], acc[ct], 0, 0, 0);
                    acc[ct] = __builtin_amdgcn_mfma_f32_16x16x32_bf16(a1, w1f[1][ct], acc[ct], 0, 0, 0);
                    acc[ct] = __builtin_amdgcn_mfma_f32_16x16x32_bf16(a2, w1f[2][ct], acc[ct], 0, 0, 0);
                }
#pragma unroll
                for (int ct = 0; ct < 4; ++ct)
#pragma unroll
                    for (int r = 0; r < 4; ++r) {
                        int rw = 16 * wv + 4 * lg + r;
                        int idx = rw * 64 + 16 * ct + lr;
                        h1s[idx ^ ((rw & 7) << 3)] = f2bf(fmaxf(acc[ct][r], 0.f));
                    }
            }
            bf16x8 ha0 = *(bf16x8*)&h1s[(arow * 64 + 0  + 8 * lg) ^ ((arow & 7) << 3)];
            bf16x8 ha1 = *(bf16x8*)&h1s[(arow * 64 + 32 + 8 * lg) ^ ((arow & 7) << 3)];
            {
                f32x4 acc[4];
#pragma unroll
                for (int ct = 0; ct < 4; ++ct) {
                    acc[ct] = (f32x4){b2v[ct], b2v[ct], b2v[ct], b2v[ct]};
                    acc[ct] = __builtin_amdgcn_mfma_f32_16x16x32_bf16(ha0, w2f[0][ct], acc[ct], 0, 0, 0);
                    acc[ct] = __builtin_amdgcn_mfma_f32_16x16x32_bf16(ha1, w2f[1][ct], acc[ct], 0, 0, 0);
                }
#pragma unroll
                for (int ct = 0; ct < 4; ++ct)
#pragma unroll
                    for (int r = 0; r < 4; ++r) {
                        int rw = 16 * wv + 4 * lg + r;
                        int idx = rw * 64 + 16 * ct + lr;
                        h2s[idx ^ ((rw & 7) << 3)] = f2bf(fmaxf(acc[ct][r], 0.f));
                    }
            }
            bf16x8 hb0 = *(bf16x8*)&h2s[(arow * 64 + 0  + 8 * lg) ^ ((arow & 7) << 3)];
            bf16x8 hb1 = *(bf16x8*)&h2s[(arow * 64 + 32 + 8 * lg) ^ ((arow & 7) << 3)];
            {
                f32x4 acc3[8];
#pragma unroll
                for (int ct = 0; ct < 8; ++ct) {
                    acc3[ct] = (f32x4){b3v[ct], b3v[ct], b3v[ct], b3v[ct]};
                    acc3[ct] = __builtin_amdgcn_mfma_f32_16x16x32_bf16(hb0, w3f[0][ct], acc3[ct], 0, 0, 0);
                    acc3[ct] = __builtin_amdgcn_mfma_f32_16x16x32_bf16(hb1, w3f[1][ct], acc3[ct], 0, 0, 0);
                }
#pragma unroll
                for (int ct = 0; ct < 8; ++ct) {
                    float m = -INFINITY;
#pragma unroll
                    for (int r = 0; r < 4; ++r) {
                        int rg = 16 * wv + 4 * lg + r;
                        float v = fmaxf(acc3[ct][r], 0.f);
                        m = (rg < C && v > m) ? v : m;
                    }
                    m = fmaxf(m, __shfl_xor(m, 16, 64));
                    m = fmaxf(m, __shfl_xor(m, 32, 64));
                    if (lg == 0) omax[wv * 128 + 16 * ct + lr] = m;
                }
            }
            __syncthreads();
            if (tid < 128) {
                float m = fmaxf(fmaxf(omax[0 * 128 + tid], omax[1 * 128 + tid]),
                                fmaxf(omax[2 * 128 + tid], omax[3 * 128 + tid]));
                out_feat[(size_t)cen * 128 + tid] = m;
            }
            __syncthreads();
        }
    }
}

extern "C" void kernel_launch(void* const* d_in, const int* in_sizes, int n_in,
                              void* d_out, int out_size, void* d_ws, size_t ws_size,
                              hipStream_t stream) {
    const float* x   = (const float*)d_in[0];
    const float* pos = (const float*)d_in[1];
    const float* W1  = (const float*)d_in[3];
    const float* b1  = (const float*)d_in[4];
    const float* W2  = (const float*)d_in[5];
    const float* b2  = (const float*)d_in[6];
    const float* W3  = (const float*)d_in[7];
    const float* b3  = (const float*)d_in[8];
    float* out = (float*)d_out;
    char* ws = (char*)d_ws;
    int*   progress = (int*)ws;                    // 16 x 128B padded slots
    float* histg    = (float*)(ws + 4096);         // [16][1024][3] = 192KB
    float* out_feat  = out;                        // [16384][128]
    float* out_pos   = out + (size_t)16384 * 128;  // [16384][3]
    float* out_batch = out + (size_t)16384 * 131;  // [16384]
    hipMemsetAsync(ws, 0, 4096, stream);
    fused_kernel<<<256, 256, 0, stream>>>(pos, x, W1, b1, W2, b2, W3, b3,
                                          out_feat, out_pos, out_batch,
                                          histg, progress);
}